// Round 1
// baseline (6774.968 us; speedup 1.0000x reference)
//
#include <hip/hip_runtime.h>
#include <hip/hip_bf16.h>

#define EPS_F 1e-10f

constexpr int B_ = 8, S_ = 4, C_ = 512, Cq_ = 128, HW_ = 4096;
constexpr long long D_ = (long long)Cq_ * HW_; // 524288 per (b,s) Q/K vector

__device__ inline float bf_lo(unsigned int u) { return __uint_as_float(u << 16); }
__device__ inline float bf_hi(unsigned int u) { return __uint_as_float(u & 0xffff0000u); }

__device__ inline unsigned int pack_bf2(float a, float b) {
    __hip_bfloat16 ha = __float2bfloat16(a);
    __hip_bfloat16 hb = __float2bfloat16(b);
    unsigned int ua = *reinterpret_cast<unsigned short*>(&ha);
    unsigned int ub = *reinterpret_cast<unsigned short*>(&hb);
    return ua | (ub << 16);
}

// ---------------------------------------------------------------------------
// Kernel 1: Q/K projection GEMMs.
//   Q[b,s] (128 x 4096) = Wq[s] (128x512) @ X[b,s] (512x4096) + bq[s]
//   stored bf16 into workspace. blockIdx.z = bs*2 + which(0=Q,1=K).
// 64x64 tile, 256 threads, 4x4 per thread, BK=32.
// ---------------------------------------------------------------------------
__global__ __launch_bounds__(256) void qk_gemm(
    const float* __restrict__ x,
    const float* __restrict__ wq, const float* __restrict__ bq,
    const float* __restrict__ wk, const float* __restrict__ bk,
    __hip_bfloat16* __restrict__ Qws, __hip_bfloat16* __restrict__ Kws) {

    const int which = blockIdx.z & 1;
    const int bs = blockIdx.z >> 1;         // 0..31
    const int s = bs & 3;
    const float* __restrict__ Wm  = which ? wk : wq;
    const float* __restrict__ bia = which ? bk : bq;
    __hip_bfloat16* __restrict__ outp = which ? Kws : Qws;

    const int o0 = blockIdx.y * 64;
    const int p0 = blockIdx.x * 64;
    const float* A  = Wm + (size_t)s * Cq_ * C_;        // [o][c]
    const float* Bx = x + (size_t)bs * C_ * HW_;        // [c][p]

    __shared__ float As[32][65];   // transposed: [c][o]
    __shared__ float Bs[32][65];   // [c][p]

    const int tid = threadIdx.x;
    const int ty = tid >> 4, tx = tid & 15;

    float acc[4][4] = {};

    for (int k0 = 0; k0 < C_; k0 += 32) {
#pragma unroll
        for (int j = 0; j < 8; ++j) {
            int l = j * 256 + tid;
            int row = l >> 5, col = l & 31;              // row=o-in-tile, col=c-in-chunk
            As[col][row] = A[(size_t)(o0 + row) * C_ + k0 + col];
        }
#pragma unroll
        for (int j = 0; j < 8; ++j) {
            int l = j * 256 + tid;
            int row = l >> 6, col = l & 63;              // row=c-in-chunk, col=p-in-tile
            Bs[row][col] = Bx[(size_t)(k0 + row) * HW_ + p0 + col];
        }
        __syncthreads();
#pragma unroll
        for (int k = 0; k < 32; ++k) {
            float a[4], bb[4];
#pragma unroll
            for (int i = 0; i < 4; ++i) a[i] = As[k][ty * 4 + i];
#pragma unroll
            for (int j = 0; j < 4; ++j) bb[j] = Bs[k][tx * 4 + j];
#pragma unroll
            for (int i = 0; i < 4; ++i)
#pragma unroll
                for (int j = 0; j < 4; ++j)
                    acc[i][j] += a[i] * bb[j];
        }
        __syncthreads();
    }

#pragma unroll
    for (int i = 0; i < 4; ++i) {
        const int o = o0 + ty * 4 + i;
        const float bval = bia[s * Cq_ + o];
        uint2 w;
        w.x = pack_bf2(acc[i][0] + bval, acc[i][1] + bval);
        w.y = pack_bf2(acc[i][2] + bval, acc[i][3] + bval);
        size_t off = ((size_t)bs * Cq_ + o) * HW_ + p0 + tx * 4;
        *reinterpret_cast<uint2*>(outp + off) = w;
    }
}

// ---------------------------------------------------------------------------
// Kernel 2: Gram reductions over D=524288.
//   u<4 : g[b][s][u]   = <Q[b,s], K[b,u]>
//   u==4: g[b][s][4]   = <Q[b,s], Q[b,s]>
//   u==5: g[b][s][5]   = <K[b,s], K[b,s]>
// one block per (u,s,b).
// ---------------------------------------------------------------------------
__global__ __launch_bounds__(256) void gram_kernel(
    const __hip_bfloat16* __restrict__ Q,
    const __hip_bfloat16* __restrict__ K,
    float* __restrict__ g) {

    const int u = blockIdx.x, s = blockIdx.y, b = blockIdx.z;
    const __hip_bfloat16 *pa, *pb;
    if (u < 4)       { pa = Q + (size_t)(b * 4 + s) * D_; pb = K + (size_t)(b * 4 + u) * D_; }
    else if (u == 4) { pa = pb = Q + (size_t)(b * 4 + s) * D_; }
    else             { pa = pb = K + (size_t)(b * 4 + s) * D_; }

    const uint4* va = reinterpret_cast<const uint4*>(pa);
    const uint4* vb = reinterpret_cast<const uint4*>(pb);
    const int n8 = (int)(D_ / 8);   // 65536 vec8 chunks

    float acc = 0.f;
    for (int i = threadIdx.x; i < n8; i += 256) {
        uint4 a = va[i], c = vb[i];
        acc += bf_lo(a.x) * bf_lo(c.x) + bf_hi(a.x) * bf_hi(c.x);
        acc += bf_lo(a.y) * bf_lo(c.y) + bf_hi(a.y) * bf_hi(c.y);
        acc += bf_lo(a.z) * bf_lo(c.z) + bf_hi(a.z) * bf_hi(c.z);
        acc += bf_lo(a.w) * bf_lo(c.w) + bf_hi(a.w) * bf_hi(c.w);
    }
#pragma unroll
    for (int off = 32; off > 0; off >>= 1) acc += __shfl_down(acc, off);

    __shared__ float wsum[4];
    const int lane = threadIdx.x & 63, wid = threadIdx.x >> 6;
    if (lane == 0) wsum[wid] = acc;
    __syncthreads();
    if (threadIdx.x == 0) {
        float tot = wsum[0] + wsum[1] + wsum[2] + wsum[3];
        g[(size_t)(b * 4 + s) * 6 + u] = tot;
    }
}

// ---------------------------------------------------------------------------
// Kernel 3: tiny — cosine energy + softmax -> att (B,S,S)
// ---------------------------------------------------------------------------
__global__ void att_kernel(const float* __restrict__ g, float* __restrict__ att) {
    const int b = threadIdx.x;
    if (b >= B_) return;
    const float* gb = g + (size_t)b * 4 * 6;
    float nq[4], nk[4];
#pragma unroll
    for (int s = 0; s < 4; ++s) {
        nq[s] = sqrtf(gb[s * 6 + 4]) + EPS_F;
        nk[s] = sqrtf(gb[s * 6 + 5]) + EPS_F;
    }
#pragma unroll
    for (int s = 0; s < 4; ++s) {
        float e[4], m = -1e30f;
#pragma unroll
        for (int t = 0; t < 4; ++t) {
            e[t] = gb[s * 6 + t] / (nq[s] * nk[t]);
            m = fmaxf(m, e[t]);
        }
        float sum = 0.f;
#pragma unroll
        for (int t = 0; t < 4; ++t) { e[t] = expf(e[t] - m); sum += e[t]; }
#pragma unroll
        for (int t = 0; t < 4; ++t) att[(size_t)(b * 4 + s) * 4 + t] = e[t] / sum;
    }
}

// ---------------------------------------------------------------------------
// Kernel 4: fused V + attention blend + bias + residual.
//   out[b,s,c,p] = gamma*( sum_t att[b,s,t]*( (Wv[t]@X[b,t])[c,p] + bv[t,c] ) ) + x[b,s,c,p]
// block computes a 64(c) x 64(p) tile for ALL 4 s outputs; loops t internally
// so V is never materialized. 256 threads, 4x4 V-microtile, 4 s accumulators.
// ---------------------------------------------------------------------------
__global__ __launch_bounds__(256) void vblend(
    const float* __restrict__ x,
    const float* __restrict__ wv, const float* __restrict__ bv,
    const float* __restrict__ att, const float* __restrict__ gamma,
    float* __restrict__ out) {

    const int b = blockIdx.z;
    const int c0 = blockIdx.y * 64;
    const int p0 = blockIdx.x * 64;
    const int tid = threadIdx.x;
    const int ty = tid >> 4, tx = tid & 15;
    const float gm = gamma[0];

    float A_[4][4];
#pragma unroll
    for (int s = 0; s < 4; ++s)
#pragma unroll
        for (int t = 0; t < 4; ++t)
            A_[s][t] = att[(size_t)(b * 4 + s) * 4 + t];

    float acc_out[4][4][4] = {};    // [s][i][j]

    __shared__ float As[32][65];
    __shared__ float Bs[32][65];

    for (int t = 0; t < 4; ++t) {
        const float* Wm = wv + (size_t)t * C_ * C_;               // [c][c']
        const float* Bx = x + (size_t)(b * 4 + t) * C_ * HW_;     // [c'][p]
        float accv[4][4] = {};
        for (int k0 = 0; k0 < C_; k0 += 32) {
#pragma unroll
            for (int j = 0; j < 8; ++j) {
                int l = j * 256 + tid;
                int row = l >> 5, col = l & 31;
                As[col][row] = Wm[(size_t)(c0 + row) * C_ + k0 + col];
            }
#pragma unroll
            for (int j = 0; j < 8; ++j) {
                int l = j * 256 + tid;
                int row = l >> 6, col = l & 63;
                Bs[row][col] = Bx[(size_t)(k0 + row) * HW_ + p0 + col];
            }
            __syncthreads();
#pragma unroll
            for (int k = 0; k < 32; ++k) {
                float a[4], bb[4];
#pragma unroll
                for (int i = 0; i < 4; ++i) a[i] = As[k][ty * 4 + i];
#pragma unroll
                for (int j = 0; j < 4; ++j) bb[j] = Bs[k][tx * 4 + j];
#pragma unroll
                for (int i = 0; i < 4; ++i)
#pragma unroll
                    for (int j = 0; j < 4; ++j)
                        accv[i][j] += a[i] * bb[j];
            }
            __syncthreads();
        }
#pragma unroll
        for (int s = 0; s < 4; ++s) {
            const float w = A_[s][t];
#pragma unroll
            for (int i = 0; i < 4; ++i)
#pragma unroll
                for (int j = 0; j < 4; ++j)
                    acc_out[s][i][j] += w * accv[i][j];
        }
    }

    // bias blend + gamma + residual, float4 stores
#pragma unroll
    for (int s = 0; s < 4; ++s) {
#pragma unroll
        for (int i = 0; i < 4; ++i) {
            const int c = c0 + ty * 4 + i;
            float bsum = 0.f;
#pragma unroll
            for (int t = 0; t < 4; ++t) bsum += A_[s][t] * bv[(size_t)t * C_ + c];
            size_t off = ((size_t)(b * 4 + s) * C_ + c) * HW_ + p0 + tx * 4;
            const float4 xr = *reinterpret_cast<const float4*>(x + off);
            float4 o;
            o.x = gm * (acc_out[s][i][0] + bsum) + xr.x;
            o.y = gm * (acc_out[s][i][1] + bsum) + xr.y;
            o.z = gm * (acc_out[s][i][2] + bsum) + xr.z;
            o.w = gm * (acc_out[s][i][3] + bsum) + xr.w;
            *reinterpret_cast<float4*>(out + off) = o;
        }
    }
}

extern "C" void kernel_launch(void* const* d_in, const int* in_sizes, int n_in,
                              void* d_out, int out_size, void* d_ws, size_t ws_size,
                              hipStream_t stream) {
    const float* x     = (const float*)d_in[0];
    const float* wq    = (const float*)d_in[1];
    const float* bq    = (const float*)d_in[2];
    const float* wk    = (const float*)d_in[3];
    const float* bk    = (const float*)d_in[4];
    const float* wv    = (const float*)d_in[5];
    const float* bv    = (const float*)d_in[6];
    const float* gamma = (const float*)d_in[7];
    float* out = (float*)d_out;

    const size_t qbytes = (size_t)B_ * S_ * Cq_ * HW_ * sizeof(__hip_bfloat16); // 33.5 MB
    __hip_bfloat16* Qws = (__hip_bfloat16*)d_ws;
    __hip_bfloat16* Kws = (__hip_bfloat16*)((char*)d_ws + qbytes);
    float* g   = (float*)((char*)d_ws + 2 * qbytes);
    float* att = g + (size_t)B_ * S_ * 6;

    // Q/K projections: grid (p-tiles=64, o-tiles=2, B*S*2=64)
    qk_gemm<<<dim3(64, 2, 64), 256, 0, stream>>>(x, wq, bq, wk, bk, Qws, Kws);
    // Gram dots/norms: grid (6, S, B)
    gram_kernel<<<dim3(6, S_, B_), 256, 0, stream>>>(Qws, Kws, g);
    // softmax (tiny)
    att_kernel<<<1, 64, 0, stream>>>(g, att);
    // fused V + blend + residual: grid (p-tiles=64, c-tiles=8, B=8)
    vblend<<<dim3(64, 8, 8), 256, 0, stream>>>(x, wv, bv, att, gamma, out);
}

// Round 2
// 513.359 us; speedup vs baseline: 13.1973x; 13.1973x over previous
//
#include <hip/hip_runtime.h>
#include <hip/hip_bf16.h>

#define EPS_F 1e-10f

typedef short s16x8 __attribute__((ext_vector_type(8)));
typedef float f32x4 __attribute__((ext_vector_type(4)));
typedef unsigned short ushort_t;

constexpr int B_ = 8, S_ = 4, C_ = 512, Cq_ = 128, HW_ = 4096;
constexpr long long D_ = (long long)Cq_ * HW_; // 524288 per (b,s) Q/K vector

__device__ inline float bf_lo(unsigned int u) { return __uint_as_float(u << 16); }
__device__ inline float bf_hi(unsigned int u) { return __uint_as_float(u & 0xffff0000u); }

__device__ inline ushort_t f2bf(float f) {
    __hip_bfloat16 h = __float2bfloat16(f);
    return *reinterpret_cast<ushort_t*>(&h);
}

// ---------------------------------------------------------------------------
// prep: fp32 -> bf16 weight conversion.
//   Wqk[s]: rows 0-127 = wq[s], rows 128-255 = wk[s]   (4 x 256 x 512)
//   Wvb[t] = wv[t]                                      (4 x 512 x 512)
// Also zeroes g4 (gram partials).
// ---------------------------------------------------------------------------
__global__ __launch_bounds__(256) void prep(
    const float* __restrict__ wq, const float* __restrict__ wk,
    const float* __restrict__ wv,
    ushort_t* __restrict__ Wqk, ushort_t* __restrict__ Wvb,
    float* __restrict__ g4) {
    int gid = blockIdx.x * 256 + threadIdx.x;
    if (gid < 4 * 256 * 512) {
        int s = gid >> 17;          // / (256*512)
        int rem = gid & 131071;
        int r = rem >> 9, c = rem & 511;
        float v = (r < 128) ? wq[((size_t)s * 128 + r) * 512 + c]
                            : wk[((size_t)s * 128 + (r - 128)) * 512 + c];
        Wqk[gid] = f2bf(v);
    } else {
        int id2 = gid - 4 * 256 * 512;   // < 4*512*512
        Wvb[id2] = f2bf(wv[id2]);
    }
    if (gid < 32 * 6 * 4) g4[gid] = 0.f;
}

// ---------------------------------------------------------------------------
// qk_mfma: per (b,t): [Wq;Wk] (256x512) @ X[b,t] (512x4096) + bias -> Q,K bf16
// BM=256 (full M), BN=64, BK=32. 512 threads = 8 waves (4 m-rows x 2 n-cols),
// wave tile 64x32, mfma_f32_16x16x32_bf16.
// A staged from bf16 global via b128 into padded LDS (stride 40 ushort).
// B staged from fp32 x with transpose+convert into XOR-swizzled LDS
// (stride 32, chunk ^= (p>>2)&3).
// ---------------------------------------------------------------------------
__global__ __launch_bounds__(512) void qk_mfma(
    const ushort_t* __restrict__ Wqk, const float* __restrict__ x,
    const float* __restrict__ bq, const float* __restrict__ bk,
    ushort_t* __restrict__ Qb, ushort_t* __restrict__ Kb) {

    const int bt = blockIdx.z;
    const int s = bt & 3;
    const int p0 = blockIdx.x * 64;
    const ushort_t* A = Wqk + (size_t)s * 256 * 512;
    const float* Bx = x + (size_t)bt * C_ * HW_;

    __shared__ __align__(16) ushort_t As[256][40];
    __shared__ __align__(16) ushort_t Bs[64][32];

    const int tid = threadIdx.x;
    const int wv = tid >> 6, lane = tid & 63;
    const int wr = wv >> 1, wc = wv & 1;
    const int li = lane & 15, lk = lane >> 4;
    const int csr = (li >> 2) & 3;                // read-side swizzle (row p -> p>>2 == li-based)

    f32x4 acc[4][2];
#pragma unroll
    for (int mf = 0; mf < 4; ++mf)
#pragma unroll
        for (int nf = 0; nf < 2; ++nf) acc[mf][nf] = 0.f;

    // B staging decomposition: k = tid>>4 (0..31), p-base = (tid&15)*4
    const int sk = tid >> 4, spb = (tid & 15) * 4;
    const int skc = sk >> 3, sko = sk & 7;

    for (int k0 = 0; k0 < C_; k0 += 32) {
        // --- stage A (256 rows x 32 bf16): 1024 16B chunks, 2 per thread ---
#pragma unroll
        for (int i = 0; i < 2; ++i) {
            int lin = tid + i * 512;
            int m = lin >> 2, ch = lin & 3;
            *reinterpret_cast<uint4*>(&As[m][ch * 8]) =
                *reinterpret_cast<const uint4*>(A + (size_t)m * 512 + k0 + ch * 8);
        }
        // --- stage B (32 k x 64 p fp32 -> transposed bf16, swizzled) ---
        {
            float4 v = *reinterpret_cast<const float4*>(
                Bx + (size_t)(k0 + sk) * HW_ + p0 + spb);
            float vv[4] = {v.x, v.y, v.z, v.w};
#pragma unroll
            for (int i = 0; i < 4; ++i) {
                int p = spb + i;
                int col = (((skc ^ ((p >> 2) & 3)) << 3) | sko);
                Bs[p][col] = f2bf(vv[i]);
            }
        }
        __syncthreads();

        s16x8 af[4], bfr[2];
#pragma unroll
        for (int mf = 0; mf < 4; ++mf)
            af[mf] = *reinterpret_cast<const s16x8*>(&As[wr * 64 + mf * 16 + li][lk * 8]);
#pragma unroll
        for (int nf = 0; nf < 2; ++nf)
            bfr[nf] = *reinterpret_cast<const s16x8*>(&Bs[wc * 32 + nf * 16 + li][((lk ^ csr) * 8)]);
#pragma unroll
        for (int mf = 0; mf < 4; ++mf)
#pragma unroll
            for (int nf = 0; nf < 2; ++nf)
                acc[mf][nf] = __builtin_amdgcn_mfma_f32_16x16x32_bf16(
                    af[mf], bfr[nf], acc[mf][nf], 0, 0, 0);
        __syncthreads();
    }

    // epilogue: +bias, write bf16 Q/K. m<128 <=> wr<2 (wave-uniform).
#pragma unroll
    for (int mf = 0; mf < 4; ++mf) {
#pragma unroll
        for (int r = 0; r < 4; ++r) {
            int m = wr * 64 + mf * 16 + lk * 4 + r;
            float bias = (m < 128) ? bq[s * 128 + m] : bk[s * 128 + (m - 128)];
#pragma unroll
            for (int nf = 0; nf < 2; ++nf) {
                int p = p0 + wc * 32 + nf * 16 + li;
                float vv = acc[mf][nf][r] + bias;
                if (m < 128)
                    Qb[(size_t)bt * D_ + (size_t)m * HW_ + p] = f2bf(vv);
                else
                    Kb[(size_t)bt * D_ + (size_t)(m - 128) * HW_ + p] = f2bf(vv);
            }
        }
    }
}

// ---------------------------------------------------------------------------
// gram_part: partial dots over D/4 chunk. Deterministic 2-stage (no atomics).
//   u<4: <Q[b,s],K[b,u]>, u==4: <Q,Q>, u==5: <K,K>  -> g4[(bs*6+u)*4+chunk]
// ---------------------------------------------------------------------------
__global__ __launch_bounds__(256) void gram_part(
    const ushort_t* __restrict__ Q, const ushort_t* __restrict__ K,
    float* __restrict__ g4) {

    const int u = blockIdx.x, ch = blockIdx.y, bs = blockIdx.z;
    const int b = bs >> 2;
    const ushort_t *pa, *pb;
    if (u < 4)       { pa = Q + (size_t)bs * D_; pb = K + (size_t)(b * 4 + u) * D_; }
    else if (u == 4) { pa = pb = Q + (size_t)bs * D_; }
    else             { pa = pb = K + (size_t)bs * D_; }

    const size_t off = (size_t)ch * (D_ / 4);
    const uint4* va = reinterpret_cast<const uint4*>(pa + off);
    const uint4* vb = reinterpret_cast<const uint4*>(pb + off);
    const int n8 = (int)(D_ / 4 / 8);   // 16384

    float acc = 0.f;
    for (int i = threadIdx.x; i < n8; i += 256) {
        uint4 a = va[i], c = vb[i];
        acc += bf_lo(a.x) * bf_lo(c.x) + bf_hi(a.x) * bf_hi(c.x);
        acc += bf_lo(a.y) * bf_lo(c.y) + bf_hi(a.y) * bf_hi(c.y);
        acc += bf_lo(a.z) * bf_lo(c.z) + bf_hi(a.z) * bf_hi(c.z);
        acc += bf_lo(a.w) * bf_lo(c.w) + bf_hi(a.w) * bf_hi(c.w);
    }
#pragma unroll
    for (int o = 32; o > 0; o >>= 1) acc += __shfl_down(acc, o);

    __shared__ float wsum[4];
    const int lane = threadIdx.x & 63, wid = threadIdx.x >> 6;
    if (lane == 0) wsum[wid] = acc;
    __syncthreads();
    if (threadIdx.x == 0)
        g4[(size_t)(bs * 6 + u) * 4 + ch] = wsum[0] + wsum[1] + wsum[2] + wsum[3];
}

// ---------------------------------------------------------------------------
// att_k: sum gram partials, cosine energy + softmax -> att (B,S,S)
// ---------------------------------------------------------------------------
__global__ void att_k(const float* __restrict__ g4, float* __restrict__ att) {
    const int b = threadIdx.x;
    if (b >= B_) return;
    auto g = [&](int s, int u) {
        const float* p = g4 + (size_t)((b * 4 + s) * 6 + u) * 4;
        return p[0] + p[1] + p[2] + p[3];
    };
    float nq[4], nk[4];
#pragma unroll
    for (int s = 0; s < 4; ++s) {
        nq[s] = sqrtf(g(s, 4)) + EPS_F;
        nk[s] = sqrtf(g(s, 5)) + EPS_F;
    }
#pragma unroll
    for (int s = 0; s < 4; ++s) {
        float e[4], m = -1e30f;
#pragma unroll
        for (int t = 0; t < 4; ++t) {
            e[t] = g(s, t) / (nq[s] * nk[t]);
            m = fmaxf(m, e[t]);
        }
        float sum = 0.f;
#pragma unroll
        for (int t = 0; t < 4; ++t) { e[t] = expf(e[t] - m); sum += e[t]; }
#pragma unroll
        for (int t = 0; t < 4; ++t) att[(size_t)(b * 4 + s) * 4 + t] = e[t] / sum;
    }
}

// ---------------------------------------------------------------------------
// vblend_mfma: fused V-GEMM + attention blend + bias + gamma + residual.
// Same tile structure as qk_mfma; loops t=0..3, blending acc into per-s
// masters in registers (V never materialized).
// ---------------------------------------------------------------------------
__global__ __launch_bounds__(512) void vblend_mfma(
    const ushort_t* __restrict__ Wvb, const float* __restrict__ x,
    const float* __restrict__ bv, const float* __restrict__ att,
    const float* __restrict__ gamma, float* __restrict__ out) {

    const int b = blockIdx.z;
    const int c0 = blockIdx.y * 256;
    const int p0 = blockIdx.x * 64;

    __shared__ __align__(16) ushort_t As[256][40];
    __shared__ __align__(16) ushort_t Bs[64][32];

    const int tid = threadIdx.x;
    const int wv = tid >> 6, lane = tid & 63;
    const int wr = wv >> 1, wc = wv & 1;
    const int li = lane & 15, lk = lane >> 4;
    const int csr = (li >> 2) & 3;
    const float gm = gamma[0];

    f32x4 mst[4][4][2];   // [s][mf][nf]
#pragma unroll
    for (int s = 0; s < 4; ++s)
#pragma unroll
        for (int mf = 0; mf < 4; ++mf)
#pragma unroll
            for (int nf = 0; nf < 2; ++nf) mst[s][mf][nf] = 0.f;

    const int sk = tid >> 4, spb = (tid & 15) * 4;
    const int skc = sk >> 3, sko = sk & 7;

    for (int t = 0; t < 4; ++t) {
        const ushort_t* A = Wvb + ((size_t)t * 512 + c0) * 512;
        const float* Bx = x + (size_t)(b * 4 + t) * C_ * HW_;

        float w4[4];
#pragma unroll
        for (int s = 0; s < 4; ++s) w4[s] = att[(size_t)(b * 4 + s) * 4 + t];

        f32x4 acc[4][2];
#pragma unroll
        for (int mf = 0; mf < 4; ++mf)
#pragma unroll
            for (int nf = 0; nf < 2; ++nf) acc[mf][nf] = 0.f;

        for (int k0 = 0; k0 < C_; k0 += 32) {
#pragma unroll
            for (int i = 0; i < 2; ++i) {
                int lin = tid + i * 512;
                int m = lin >> 2, ch = lin & 3;
                *reinterpret_cast<uint4*>(&As[m][ch * 8]) =
                    *reinterpret_cast<const uint4*>(A + (size_t)m * 512 + k0 + ch * 8);
            }
            {
                float4 v = *reinterpret_cast<const float4*>(
                    Bx + (size_t)(k0 + sk) * HW_ + p0 + spb);
                float vv[4] = {v.x, v.y, v.z, v.w};
#pragma unroll
                for (int i = 0; i < 4; ++i) {
                    int p = spb + i;
                    int col = (((skc ^ ((p >> 2) & 3)) << 3) | sko);
                    Bs[p][col] = f2bf(vv[i]);
                }
            }
            __syncthreads();

            s16x8 af[4], bfr[2];
#pragma unroll
            for (int mf = 0; mf < 4; ++mf)
                af[mf] = *reinterpret_cast<const s16x8*>(&As[wr * 64 + mf * 16 + li][lk * 8]);
#pragma unroll
            for (int nf = 0; nf < 2; ++nf)
                bfr[nf] = *reinterpret_cast<const s16x8*>(&Bs[wc * 32 + nf * 16 + li][((lk ^ csr) * 8)]);
#pragma unroll
            for (int mf = 0; mf < 4; ++mf)
#pragma unroll
                for (int nf = 0; nf < 2; ++nf)
                    acc[mf][nf] = __builtin_amdgcn_mfma_f32_16x16x32_bf16(
                        af[mf], bfr[nf], acc[mf][nf], 0, 0, 0);
            __syncthreads();
        }

#pragma unroll
        for (int s = 0; s < 4; ++s)
#pragma unroll
            for (int mf = 0; mf < 4; ++mf)
#pragma unroll
                for (int nf = 0; nf < 2; ++nf)
                    mst[s][mf][nf] += w4[s] * acc[mf][nf];
    }

    // epilogue: out = gm*(mst + sum_t att*bv) + x
#pragma unroll
    for (int mf = 0; mf < 4; ++mf) {
#pragma unroll
        for (int r = 0; r < 4; ++r) {
            int c = c0 + wr * 64 + mf * 16 + lk * 4 + r;
            float bvv[4];
#pragma unroll
            for (int t = 0; t < 4; ++t) bvv[t] = bv[(size_t)t * 512 + c];
#pragma unroll
            for (int s = 0; s < 4; ++s) {
                float a0 = att[(size_t)(b * 4 + s) * 4 + 0];
                float a1 = att[(size_t)(b * 4 + s) * 4 + 1];
                float a2 = att[(size_t)(b * 4 + s) * 4 + 2];
                float a3 = att[(size_t)(b * 4 + s) * 4 + 3];
                float bsum = a0 * bvv[0] + a1 * bvv[1] + a2 * bvv[2] + a3 * bvv[3];
#pragma unroll
                for (int nf = 0; nf < 2; ++nf) {
                    int p = p0 + wc * 32 + nf * 16 + li;
                    size_t off = ((size_t)(b * 4 + s) * C_ + c) * HW_ + p;
                    out[off] = gm * (mst[s][mf][nf][r] + bsum) + x[off];
                }
            }
        }
    }
}

extern "C" void kernel_launch(void* const* d_in, const int* in_sizes, int n_in,
                              void* d_out, int out_size, void* d_ws, size_t ws_size,
                              hipStream_t stream) {
    const float* x     = (const float*)d_in[0];
    const float* wq    = (const float*)d_in[1];
    const float* bq    = (const float*)d_in[2];
    const float* wk    = (const float*)d_in[3];
    const float* bk    = (const float*)d_in[4];
    const float* wv    = (const float*)d_in[5];
    const float* bv    = (const float*)d_in[6];
    const float* gamma = (const float*)d_in[7];
    float* out = (float*)d_out;

    // workspace layout (bytes)
    char* ws = (char*)d_ws;
    const size_t qk_elems = (size_t)B_ * S_ * Cq_ * HW_;       // 16,777,216
    ushort_t* Qb  = (ushort_t*)ws;                              // 33.55 MB
    ushort_t* Kb  = Qb + qk_elems;                              // 33.55 MB
    ushort_t* Wqk = Kb + qk_elems;                              // 1.05 MB
    ushort_t* Wvb = Wqk + (size_t)4 * 256 * 512;                // 2.10 MB
    float*    g4  = (float*)(Wvb + (size_t)4 * 512 * 512);      // 3 KB
    float*    att = g4 + 32 * 6 * 4;

    // 1) weight conversion + g4 zero
    prep<<<6144, 256, 0, stream>>>(wq, wk, wv, Wqk, Wvb, g4);
    // 2) Q/K projection (MFMA): grid (p-tiles, 1, b*t)
    qk_mfma<<<dim3(64, 1, 32), 512, 0, stream>>>(Wqk, x, bq, bk, Qb, Kb);
    // 3) gram partials: (u, chunk, bs)
    gram_part<<<dim3(6, 4, 32), 256, 0, stream>>>(Qb, Kb, g4);
    // 4) softmax (tiny)
    att_k<<<1, 64, 0, stream>>>(g4, att);
    // 5) fused V + blend + residual: (p-tiles, c-tiles, b)
    vblend_mfma<<<dim3(64, 2, 8), 512, 0, stream>>>(Wvb, x, bv, att, gamma, out);
}

// Round 3
// 414.012 us; speedup vs baseline: 16.3642x; 1.2400x over previous
//
#include <hip/hip_runtime.h>
#include <hip/hip_bf16.h>

#define EPS_F 1e-10f

typedef short s16x8 __attribute__((ext_vector_type(8)));
typedef float f32x4 __attribute__((ext_vector_type(4)));
typedef unsigned short ushort_t;

constexpr int B_ = 8, S_ = 4, C_ = 512, Cq_ = 128, HW_ = 4096;
constexpr long long D_ = (long long)Cq_ * HW_;

__device__ inline float bf_lo(unsigned int u) { return __uint_as_float(u << 16); }
__device__ inline float bf_hi(unsigned int u) { return __uint_as_float(u & 0xffff0000u); }

__device__ inline ushort_t f2bf(float f) {
    __hip_bfloat16 h = __float2bfloat16(f);
    return *reinterpret_cast<ushort_t*>(&h);
}
__device__ inline unsigned int pack_bf2(float a, float b) {
    return (unsigned int)f2bf(a) | ((unsigned int)f2bf(b) << 16);
}

// global(AS1) -> LDS(AS3) 16B direct load; LDS dest = uniform base + lane*16
#define GLOAD16(gp, lp) __builtin_amdgcn_global_load_lds( \
    (const __attribute__((address_space(1))) unsigned int*)(gp), \
    (__attribute__((address_space(3))) unsigned int*)(lp), 16, 0, 0)

// ---------------------------------------------------------------------------
// prep3: fp32->bf16 weights, PRE-SWIZZLED for global_load_lds + conflict-free
// ds_read_b128. Layout (16B chunk granularity):
//   Wqk_pre[s][kt][row(256)][slot(8)] holds wq/wk[s][row][kt*64 + (slot^(row&7))*8 ..+8]
//   Wvb_pre[t][ct][kt][row(256)][slot(8)] holds wv[t][ct*256+row][kt*64 + (slot^(row&7))*8 ..+8]
// Also zeroes g4.
// ---------------------------------------------------------------------------
__global__ __launch_bounds__(256) void prep3(
    const float* __restrict__ wq, const float* __restrict__ wk,
    const float* __restrict__ wv,
    ushort_t* __restrict__ Wqk_pre, ushort_t* __restrict__ Wvb_pre,
    float* __restrict__ g4) {
    int gid = blockIdx.x * 256 + threadIdx.x;
    if (gid < 32 * 6 * 4) g4[gid] = 0.f;
    if (gid < 65536) {                      // Wqk chunks
        int s = gid >> 14;
        int kt = (gid >> 11) & 7;
        int row = (gid >> 3) & 255;
        int slot = gid & 7;
        int col = kt * 64 + ((slot ^ (row & 7)) << 3);
        const float* src = (row < 128)
            ? &wq[((size_t)s * 128 + row) * 512 + col]
            : &wk[((size_t)s * 128 + (row - 128)) * 512 + col];
        float4 f0 = *reinterpret_cast<const float4*>(src);
        float4 f1 = *reinterpret_cast<const float4*>(src + 4);
        uint4 o;
        o.x = pack_bf2(f0.x, f0.y); o.y = pack_bf2(f0.z, f0.w);
        o.z = pack_bf2(f1.x, f1.y); o.w = pack_bf2(f1.z, f1.w);
        *reinterpret_cast<uint4*>(Wqk_pre + (size_t)gid * 8) = o;
    } else {                                 // Wvb chunks
        int c2 = gid - 65536;                // < 131072
        int t = c2 >> 15;
        int ct = (c2 >> 14) & 1;
        int kt = (c2 >> 11) & 7;
        int row = (c2 >> 3) & 255;
        int slot = c2 & 7;
        int col = kt * 64 + ((slot ^ (row & 7)) << 3);
        const float* src = &wv[((size_t)t * 512 + ct * 256 + row) * 512 + col];
        float4 f0 = *reinterpret_cast<const float4*>(src);
        float4 f1 = *reinterpret_cast<const float4*>(src + 4);
        uint4 o;
        o.x = pack_bf2(f0.x, f0.y); o.y = pack_bf2(f0.z, f0.w);
        o.z = pack_bf2(f1.x, f1.y); o.w = pack_bf2(f1.z, f1.w);
        *reinterpret_cast<uint4*>(Wvb_pre + (size_t)c2 * 8) = o;
    }
}

// ---------------------------------------------------------------------------
// Shared GEMM-step helpers (BM=256, BN=64, BK=64, 512 thr = 8 waves 4x2,
// wave tile 64x32, mfma_f32_16x16x32_bf16 x16 per step).
// A LDS: [256 rows][8 slots][8 bf16] linear (gload_lds), slot = c ^ (row&7).
// B LDS: [64 p][8 slots][8 bf16], slot = c ^ ((p>>3)&7)  (write conflict-free).
// ---------------------------------------------------------------------------
#define STAGE_A(tilebase, buf, Asarr)                                        \
    {                                                                        \
        const ushort_t* _tp = (tilebase);                                    \
        _Pragma("unroll")                                                    \
        for (int _i = 0; _i < 4; ++_i)                                       \
            GLOAD16(_tp + ((w4 + _i) << 9) + (lane << 3),                    \
                    &Asarr[buf][(w4 + _i) << 9]);                            \
    }

#define COMPUTE_STEP(buf, Asarr, Bsarr, accv)                                \
    {                                                                        \
        _Pragma("unroll")                                                    \
        for (int h = 0; h < 2; ++h) {                                        \
            s16x8 af0, af1, af2, af3, bf0, bf1;                              \
            af0 = *reinterpret_cast<const s16x8*>(                           \
                &Asarr[buf][(arow + 0 * 16 + li) * 64 + a_sl[h]]);           \
            af1 = *reinterpret_cast<const s16x8*>(                           \
                &Asarr[buf][(arow + 1 * 16 + li) * 64 + a_sl[h]]);           \
            af2 = *reinterpret_cast<const s16x8*>(                           \
                &Asarr[buf][(arow + 2 * 16 + li) * 64 + a_sl[h]]);           \
            af3 = *reinterpret_cast<const s16x8*>(                           \
                &Asarr[buf][(arow + 3 * 16 + li) * 64 + a_sl[h]]);           \
            bf0 = *reinterpret_cast<const s16x8*>(                           \
                &Bsarr[buf][bp0 * 64 + b_sl0[h]]);                           \
            bf1 = *reinterpret_cast<const s16x8*>(                           \
                &Bsarr[buf][bp1 * 64 + b_sl1[h]]);                           \
            accv[0][0] = __builtin_amdgcn_mfma_f32_16x16x32_bf16(af0, bf0, accv[0][0], 0, 0, 0); \
            accv[0][1] = __builtin_amdgcn_mfma_f32_16x16x32_bf16(af0, bf1, accv[0][1], 0, 0, 0); \
            accv[1][0] = __builtin_amdgcn_mfma_f32_16x16x32_bf16(af1, bf0, accv[1][0], 0, 0, 0); \
            accv[1][1] = __builtin_amdgcn_mfma_f32_16x16x32_bf16(af1, bf1, accv[1][1], 0, 0, 0); \
            accv[2][0] = __builtin_amdgcn_mfma_f32_16x16x32_bf16(af2, bf0, accv[2][0], 0, 0, 0); \
            accv[2][1] = __builtin_amdgcn_mfma_f32_16x16x32_bf16(af2, bf1, accv[2][1], 0, 0, 0); \
            accv[3][0] = __builtin_amdgcn_mfma_f32_16x16x32_bf16(af3, bf0, accv[3][0], 0, 0, 0); \
            accv[3][1] = __builtin_amdgcn_mfma_f32_16x16x32_bf16(af3, bf1, accv[3][1], 0, 0, 0); \
        }                                                                    \
    }

#define WRITE_B(buf, Bsarr, v0, v1)                                          \
    {                                                                        \
        float _vv[8] = {v0.x, v0.y, v0.z, v0.w, v1.x, v1.y, v1.z, v1.w};     \
        ushort_t* _d = &Bsarr[buf][bwbase];                                  \
        _Pragma("unroll")                                                    \
        for (int _j = 0; _j < 8; ++_j) _d[_j * 64] = f2bf(_vv[_j]);          \
    }

// ---------------------------------------------------------------------------
// qk3: [Wq;Wk](256x512) @ X[b,t](512x4096) + bias -> Qb, Kb (bf16)
// ---------------------------------------------------------------------------
__global__ __launch_bounds__(512) void qk3(
    const ushort_t* __restrict__ Wqk_pre, const float* __restrict__ x,
    const float* __restrict__ bq, const float* __restrict__ bk,
    ushort_t* __restrict__ Qb, ushort_t* __restrict__ Kb) {

    const int bt = blockIdx.z;
    const int s = bt & 3;
    const int p0 = blockIdx.x * 64;

    __shared__ __align__(16) ushort_t As[2][16384];
    __shared__ __align__(16) ushort_t Bs[2][4096];

    const int tid = threadIdx.x;
    const int w = tid >> 6, lane = tid & 63;
    const int w4 = w * 4;
    const int wr = w >> 1, wc = w & 1;
    const int li = lane & 15, lk = lane >> 4;
    const int arow = wr * 64;
    // fragment slot offsets (ushort units): slot = (h*4+lk) ^ swz, *8
    int a_sl[2], b_sl0[2], b_sl1[2];
    const int bp0 = wc * 32 + 0 * 16 + li, bp1 = wc * 32 + 1 * 16 + li;
#pragma unroll
    for (int h = 0; h < 2; ++h) {
        a_sl[h] = (((h * 4 + lk) ^ (li & 7)) << 3);
        b_sl0[h] = (((h * 4 + lk) ^ ((bp0 >> 3) & 7)) << 3);
        b_sl1[h] = (((h * 4 + lk) ^ ((bp1 >> 3) & 7)) << 3);
    }
    // B staging: thread -> k=tid>>3 (0..63), p = (tid&7)*8 ..+7
    const int sk = tid >> 3, sp = (tid & 7) * 8;
    const int bwbase = sp * 64 + (((sk >> 3) ^ (tid & 7)) << 3) + (sk & 7);

    const float* Bx = x + (size_t)bt * C_ * HW_ + p0 + sp;

    f32x4 acc[4][2];
#pragma unroll
    for (int mf = 0; mf < 4; ++mf)
#pragma unroll
        for (int nf = 0; nf < 2; ++nf) acc[mf][nf] = 0.f;

    // prologue: stage step 0
    STAGE_A(Wqk_pre + (((size_t)s * 8 + 0) << 14), 0, As);
    {
        const float* src = Bx + (size_t)sk * HW_;
        float4 v0 = *reinterpret_cast<const float4*>(src);
        float4 v1 = *reinterpret_cast<const float4*>(src + 4);
        WRITE_B(0, Bs, v0, v1);
    }
    __syncthreads();

    int cur = 0;
    for (int st = 0; st < 8; ++st) {
        float4 nb0, nb1;
        const bool more = (st < 7);
        if (more) {
            STAGE_A(Wqk_pre + (((size_t)s * 8 + st + 1) << 14), cur ^ 1, As);
            const float* src = Bx + (size_t)((st + 1) * 64 + sk) * HW_;
            nb0 = *reinterpret_cast<const float4*>(src);
            nb1 = *reinterpret_cast<const float4*>(src + 4);
        }
        COMPUTE_STEP(cur, As, Bs, acc);
        if (more) {
            WRITE_B(cur ^ 1, Bs, nb0, nb1);
            __syncthreads();
            cur ^= 1;
        }
    }

    // epilogue: +bias, split Q/K (wave-uniform: wr<2 -> Q)
#pragma unroll
    for (int mf = 0; mf < 4; ++mf) {
#pragma unroll
        for (int r = 0; r < 4; ++r) {
            int m = wr * 64 + mf * 16 + lk * 4 + r;
            float bias = (m < 128) ? bq[s * 128 + m] : bk[s * 128 + (m - 128)];
#pragma unroll
            for (int nf = 0; nf < 2; ++nf) {
                int p = p0 + wc * 32 + nf * 16 + li;
                float vv = acc[mf][nf][r] + bias;
                if (m < 128)
                    Qb[(size_t)bt * D_ + (size_t)m * HW_ + p] = f2bf(vv);
                else
                    Kb[(size_t)bt * D_ + (size_t)(m - 128) * HW_ + p] = f2bf(vv);
            }
        }
    }
}

// ---------------------------------------------------------------------------
// gram_part: partial dots over D/4 chunk (deterministic 2-stage).
// ---------------------------------------------------------------------------
__global__ __launch_bounds__(256) void gram_part(
    const ushort_t* __restrict__ Q, const ushort_t* __restrict__ K,
    float* __restrict__ g4) {

    const int u = blockIdx.x, ch = blockIdx.y, bs = blockIdx.z;
    const int b = bs >> 2;
    const ushort_t *pa, *pb;
    if (u < 4)       { pa = Q + (size_t)bs * D_; pb = K + (size_t)(b * 4 + u) * D_; }
    else if (u == 4) { pa = pb = Q + (size_t)bs * D_; }
    else             { pa = pb = K + (size_t)bs * D_; }

    const size_t off = (size_t)ch * (D_ / 4);
    const uint4* va = reinterpret_cast<const uint4*>(pa + off);
    const uint4* vb = reinterpret_cast<const uint4*>(pb + off);
    const int n8 = (int)(D_ / 4 / 8);

    float acc = 0.f;
    for (int i = threadIdx.x; i < n8; i += 256) {
        uint4 a = va[i], c = vb[i];
        acc += bf_lo(a.x) * bf_lo(c.x) + bf_hi(a.x) * bf_hi(c.x);
        acc += bf_lo(a.y) * bf_lo(c.y) + bf_hi(a.y) * bf_hi(c.y);
        acc += bf_lo(a.z) * bf_lo(c.z) + bf_hi(a.z) * bf_hi(c.z);
        acc += bf_lo(a.w) * bf_lo(c.w) + bf_hi(a.w) * bf_hi(c.w);
    }
#pragma unroll
    for (int o = 32; o > 0; o >>= 1) acc += __shfl_down(acc, o);

    __shared__ float wsum[4];
    const int lane = threadIdx.x & 63, wid = threadIdx.x >> 6;
    if (lane == 0) wsum[wid] = acc;
    __syncthreads();
    if (threadIdx.x == 0)
        g4[(size_t)(bs * 6 + u) * 4 + ch] = wsum[0] + wsum[1] + wsum[2] + wsum[3];
}

__global__ void att_k(const float* __restrict__ g4, float* __restrict__ att) {
    const int b = threadIdx.x;
    if (b >= B_) return;
    auto g = [&](int s, int u) {
        const float* p = g4 + (size_t)((b * 4 + s) * 6 + u) * 4;
        return p[0] + p[1] + p[2] + p[3];
    };
    float nq[4], nk[4];
#pragma unroll
    for (int s = 0; s < 4; ++s) {
        nq[s] = sqrtf(g(s, 4)) + EPS_F;
        nk[s] = sqrtf(g(s, 5)) + EPS_F;
    }
#pragma unroll
    for (int s = 0; s < 4; ++s) {
        float e[4], m = -1e30f;
#pragma unroll
        for (int t = 0; t < 4; ++t) {
            e[t] = g(s, t) / (nq[s] * nk[t]);
            m = fmaxf(m, e[t]);
        }
        float sum = 0.f;
#pragma unroll
        for (int t = 0; t < 4; ++t) { e[t] = expf(e[t] - m); sum += e[t]; }
#pragma unroll
        for (int t = 0; t < 4; ++t) att[(size_t)(b * 4 + s) * 4 + t] = e[t] / sum;
    }
}

// ---------------------------------------------------------------------------
// vblend3: fused V-GEMM + attention blend + bias + gamma + residual.
// 32 pipelined steps (4 t x 8 kt); per-s masters in registers.
// ---------------------------------------------------------------------------
__global__ __launch_bounds__(512) void vblend3(
    const ushort_t* __restrict__ Wvb_pre, const float* __restrict__ x,
    const float* __restrict__ bv, const float* __restrict__ att,
    const float* __restrict__ gamma, float* __restrict__ out) {

    const int b = blockIdx.z;
    const int ct = blockIdx.y;
    const int p0 = blockIdx.x * 64;

    __shared__ __align__(16) ushort_t As[2][16384];
    __shared__ __align__(16) ushort_t Bs[2][4096];

    const int tid = threadIdx.x;
    const int w = tid >> 6, lane = tid & 63;
    const int w4 = w * 4;
    const int wr = w >> 1, wc = w & 1;
    const int li = lane & 15, lk = lane >> 4;
    const int arow = wr * 64;
    int a_sl[2], b_sl0[2], b_sl1[2];
    const int bp0 = wc * 32 + 0 * 16 + li, bp1 = wc * 32 + 1 * 16 + li;
#pragma unroll
    for (int h = 0; h < 2; ++h) {
        a_sl[h] = (((h * 4 + lk) ^ (li & 7)) << 3);
        b_sl0[h] = (((h * 4 + lk) ^ ((bp0 >> 3) & 7)) << 3);
        b_sl1[h] = (((h * 4 + lk) ^ ((bp1 >> 3) & 7)) << 3);
    }
    const int sk = tid >> 3, sp = (tid & 7) * 8;
    const int bwbase = sp * 64 + (((sk >> 3) ^ (tid & 7)) << 3) + (sk & 7);
    const float gm = gamma[0];

    f32x4 mst[4][4][2];
#pragma unroll
    for (int so = 0; so < 4; ++so)
#pragma unroll
        for (int mf = 0; mf < 4; ++mf)
#pragma unroll
            for (int nf = 0; nf < 2; ++nf) mst[so][mf][nf] = 0.f;

    f32x4 acc[4][2];
#pragma unroll
    for (int mf = 0; mf < 4; ++mf)
#pragma unroll
        for (int nf = 0; nf < 2; ++nf) acc[mf][nf] = 0.f;

    // A tile base: Wvb_pre + ((t*2+ct)*8 + kt)*16384
    // B src: x[(b*4+t)*512 + kt*64 + sk][p0 + sp ..]
    STAGE_A(Wvb_pre + (((size_t)(0 * 2 + ct) * 8 + 0) << 14), 0, As);
    {
        const float* src = x + ((size_t)(b * 4 + 0) * 512 + sk) * HW_ + p0 + sp;
        float4 v0 = *reinterpret_cast<const float4*>(src);
        float4 v1 = *reinterpret_cast<const float4*>(src + 4);
        WRITE_B(0, Bs, v0, v1);
    }
    __syncthreads();

    int cur = 0;
    for (int st = 0; st < 32; ++st) {
        float4 nb0, nb1;
        const bool more = (st < 31);
        if (more) {
            const int t2 = (st + 1) >> 3, kt2 = (st + 1) & 7;
            STAGE_A(Wvb_pre + (((size_t)(t2 * 2 + ct) * 8 + kt2) << 14), cur ^ 1, As);
            const float* src =
                x + ((size_t)(b * 4 + t2) * 512 + kt2 * 64 + sk) * HW_ + p0 + sp;
            nb0 = *reinterpret_cast<const float4*>(src);
            nb1 = *reinterpret_cast<const float4*>(src + 4);
        }
        COMPUTE_STEP(cur, As, Bs, acc);
        if ((st & 7) == 7) {   // t-boundary: blend acc into masters, reset
            const int t = st >> 3;
#pragma unroll
            for (int so = 0; so < 4; ++so) {
                const float wt = att[(size_t)(b * 4 + so) * 4 + t];
#pragma unroll
                for (int mf = 0; mf < 4; ++mf)
#pragma unroll
                    for (int nf = 0; nf < 2; ++nf)
                        mst[so][mf][nf] += wt * acc[mf][nf];
            }
#pragma unroll
            for (int mf = 0; mf < 4; ++mf)
#pragma unroll
                for (int nf = 0; nf < 2; ++nf) acc[mf][nf] = 0.f;
        }
        if (more) {
            WRITE_B(cur ^ 1, Bs, nb0, nb1);
            __syncthreads();
            cur ^= 1;
        }
    }

    // epilogue: out = gm*(mst + sum_t att*bv) + x
    const int c0 = ct * 256;
#pragma unroll
    for (int mf = 0; mf < 4; ++mf) {
#pragma unroll
        for (int r = 0; r < 4; ++r) {
            int c = c0 + wr * 64 + mf * 16 + lk * 4 + r;
            float bvv[4];
#pragma unroll
            for (int t = 0; t < 4; ++t) bvv[t] = bv[(size_t)t * 512 + c];
#pragma unroll
            for (int so = 0; so < 4; ++so) {
                float a0 = att[(size_t)(b * 4 + so) * 4 + 0];
                float a1 = att[(size_t)(b * 4 + so) * 4 + 1];
                float a2 = att[(size_t)(b * 4 + so) * 4 + 2];
                float a3 = att[(size_t)(b * 4 + so) * 4 + 3];
                float bsum = a0 * bvv[0] + a1 * bvv[1] + a2 * bvv[2] + a3 * bvv[3];
#pragma unroll
                for (int nf = 0; nf < 2; ++nf) {
                    int p = p0 + wc * 32 + nf * 16 + li;
                    size_t off = ((size_t)(b * 4 + so) * C_ + c) * HW_ + p;
                    out[off] = gm * (mst[so][mf][nf][r] + bsum) + x[off];
                }
            }
        }
    }
}

extern "C" void kernel_launch(void* const* d_in, const int* in_sizes, int n_in,
                              void* d_out, int out_size, void* d_ws, size_t ws_size,
                              hipStream_t stream) {
    const float* x     = (const float*)d_in[0];
    const float* wq    = (const float*)d_in[1];
    const float* bq    = (const float*)d_in[2];
    const float* wk    = (const float*)d_in[3];
    const float* bk    = (const float*)d_in[4];
    const float* wv    = (const float*)d_in[5];
    const float* bv    = (const float*)d_in[6];
    const float* gamma = (const float*)d_in[7];
    float* out = (float*)d_out;

    char* ws = (char*)d_ws;
    const size_t qk_elems = (size_t)B_ * S_ * Cq_ * HW_;   // 16,777,216
    ushort_t* Qb      = (ushort_t*)ws;                     // 33.55 MB
    ushort_t* Kb      = Qb + qk_elems;                     // 33.55 MB
    ushort_t* Wqk_pre = Kb + qk_elems;                     // 1.05 MB
    ushort_t* Wvb_pre = Wqk_pre + (size_t)4 * 8 * 256 * 64;    // 2.10 MB
    float*    g4      = (float*)(Wvb_pre + (size_t)4 * 2 * 8 * 256 * 64);
    float*    att     = g4 + 32 * 6 * 4;

    prep3<<<768, 256, 0, stream>>>(wq, wk, wv, Wqk_pre, Wvb_pre, g4);
    qk3<<<dim3(64, 1, 32), 512, 0, stream>>>(Wqk_pre, x, bq, bk, Qb, Kb);
    gram_part<<<dim3(6, 4, 32), 256, 0, stream>>>(Qb, Kb, g4);
    att_k<<<1, 64, 0, stream>>>(g4, att);
    vblend3<<<dim3(64, 2, 8), 512, 0, stream>>>(Wvb_pre, x, bv, att, gamma, out);
}